// Round 8
// baseline (18087.083 us; speedup 1.0000x reference)
//
#include <hip/hip_runtime.h>
#include <string.h>

#define T_STEPS 256
#define B_SZ    128
#define S_SZ    512
#define D_SZ    256
#define NG      1024   // 4*HID

// ---- static device scratch (graph-capture safe, ws_size-independent) ----
__device__ float g_projT[(size_t)B_SZ * 256 * 512];     // 64 MiB, [b][d][s] fp32 (TRANSPOSED)
__device__ float g_E[(size_t)T_STEPS * B_SZ * 1024];    // 128 MiB, [t][b][j]: emb@W_ih_emb.T
__device__ float g_WihT[512 * 1024];                    // [k][j] fp32 (k<256 emb rows, k>=256 ctx rows)
__device__ float g_WhhT[256 * 1024];                    // [k][j] fp32
__device__ float g_WhT [256 * 256];                     // [k][d] fp32
__device__ float g_bias[1024];

__device__ __forceinline__ float tanh_f(float x){
    float r = __expf(2.f * x);          // exp(+inf)=inf, exp(-inf)=0 -> no NaN
    return 1.f - 2.f / (r + 1.f);
}
__device__ __forceinline__ float sigm_f(float x){
    return 1.f / (1.f + __expf(-x));
}

// ---- packing kernels ----
// W_attn: [256][512] -> W_hT [k=256][d=256] (W_m read directly by the GEMM)
__global__ void pack_attn(const float* __restrict__ W_attn){
    int id = blockIdx.x * 256 + threadIdx.x;   // 65536
    int d = id >> 8, k = id & 255;
    g_WhT[k * 256 + d] = W_attn[d * 512 + k];
}
__global__ void pack_wih(const float* __restrict__ W){
    int id = blockIdx.x * 256 + threadIdx.x;   // 524288
    int j = id >> 9, k = id & 511;
    g_WihT[k * 1024 + j] = W[id];
}
__global__ void pack_whh(const float* __restrict__ W){
    int id = blockIdx.x * 256 + threadIdx.x;   // 262144
    int j = id >> 8, k = id & 255;
    g_WhhT[k * 1024 + j] = W[id];
}
__global__ void pack_bias(const float* __restrict__ bih, const float* __restrict__ bhh){
    int j = blockIdx.x * 256 + threadIdx.x;    // 1024
    g_bias[j] = bih[j] + bhh[j];
}

// g_projT[b][d][s] = sum_e memory[s][b][e] * W_attn[d][256+e] + b_attn[d]
// GEMM: M = d (256), N = r = b*512+s (65536), K = e (256).
__global__ __launch_bounds__(256) void mem_projT_gemm(
        const float* __restrict__ memory,     // [S][B][256] fp32
        const float* __restrict__ W_attn,     // [256][512] fp32
        const float* __restrict__ b_attn){
    __shared__ float As[32][65];   // [e'][d']
    __shared__ float Bs[32][65];   // [e'][r']
    int tid = threadIdx.x;
    int tm = tid >> 4, tn = tid & 15;
    int row0 = blockIdx.x * 64;              // d tile (4 tiles)
    int col0 = blockIdx.y * 64;              // r tile (1024 tiles); 64 | 512 so one b per tile
    float acc[4][4] = {};
    for (int k0 = 0; k0 < 256; k0 += 32){
        int m = tid >> 2, kq = tid & 3;
        const float* ap = W_attn + (size_t)(row0 + m) * 512 + 256 + k0 + kq * 8;
        #pragma unroll
        for (int i = 0; i < 8; ++i) As[kq * 8 + i][m] = ap[i];
        int r  = col0 + m;
        int bb = r >> 9, ss = r & 511;
        const float* bp = memory + ((size_t)ss * B_SZ + bb) * 256 + k0 + kq * 8;
        #pragma unroll
        for (int i = 0; i < 8; ++i) Bs[kq * 8 + i][m] = bp[i];
        __syncthreads();
        #pragma unroll
        for (int k2 = 0; k2 < 32; ++k2){
            float a[4], bv[4];
            #pragma unroll
            for (int i = 0; i < 4; ++i) a[i]  = As[k2][tm * 4 + i];
            #pragma unroll
            for (int i = 0; i < 4; ++i) bv[i] = Bs[k2][tn * 4 + i];
            #pragma unroll
            for (int i = 0; i < 4; ++i)
                #pragma unroll
                for (int j = 0; j < 4; ++j) acc[i][j] += a[i] * bv[j];
        }
        __syncthreads();
    }
    int bb_o = col0 >> 9;
    int s_o  = (col0 & 511) + tn * 4;
    #pragma unroll
    for (int i = 0; i < 4; ++i){
        int d = row0 + tm * 4 + i;
        float bi = b_attn[d];
        float* pp = g_projT + ((size_t)bb_o * 256 + d) * 512 + s_o;
        #pragma unroll
        for (int j = 0; j < 4; ++j)
            pp[j] = acc[i][j] + bi;       // coalesced along s
    }
}

// g_E [r=t*B+b][j] = tgt[r][:256] @ g_WihT[k<256][j]
__global__ __launch_bounds__(256) void emb_gemm(
        const float* __restrict__ tgt){       // [T][B][256] fp32
    __shared__ float As[32][65];
    __shared__ float Bs[32][65];
    int tid = threadIdx.x;
    int tm = tid >> 4, tn = tid & 15;
    int row0 = blockIdx.x * 64;
    int col0 = blockIdx.y * 64;
    float acc[4][4] = {};
    for (int k0 = 0; k0 < 256; k0 += 32){
        int m = tid >> 2, kq = tid & 3;
        const float* ap = tgt + (size_t)(row0 + m) * 256 + k0 + kq * 8;
        #pragma unroll
        for (int i = 0; i < 8; ++i) As[kq * 8 + i][m] = ap[i];
        int kk = tid >> 3, dq = tid & 7;
        const float* bp = g_WihT + (size_t)(k0 + kk) * 1024 + col0 + dq * 8;
        #pragma unroll
        for (int i = 0; i < 8; ++i) Bs[kk][dq * 8 + i] = bp[i];
        __syncthreads();
        #pragma unroll
        for (int k2 = 0; k2 < 32; ++k2){
            float a[4], bv[4];
            #pragma unroll
            for (int i = 0; i < 4; ++i) a[i]  = As[k2][tm * 4 + i];
            #pragma unroll
            for (int i = 0; i < 4; ++i) bv[i] = Bs[k2][tn * 4 + i];
            #pragma unroll
            for (int i = 0; i < 4; ++i)
                #pragma unroll
                for (int j = 0; j < 4; ++j) acc[i][j] += a[i] * bv[j];
        }
        __syncthreads();
    }
    #pragma unroll
    for (int i = 0; i < 4; ++i){
        int r = row0 + tm * 4 + i;
        float* pp = g_E + (size_t)r * 1024 + col0 + tn * 4;
        #pragma unroll
        for (int j = 0; j < 4; ++j)
            __builtin_nontemporal_store(acc[i][j], pp + j);
    }
}

// ---- main persistent scan: one block per batch element, 1024 threads ----
__global__ __launch_bounds__(1024) void decode_scan(
        const float* __restrict__ memory,    // [S][B][256] fp32
        float* __restrict__ out)             // [T][B][256] fp32
{
    const int b    = blockIdx.x;
    const int tid  = threadIdx.x;
    const int lane = tid & 63;
    const int wave = tid >> 6;          // 16 waves

    __shared__ __align__(16) float h_s[256];
    __shared__ __align__(16) float c_s[256];
    __shared__ __align__(16) float hWh_part[4][256];
    __shared__ __align__(16) float hWh[256];
    __shared__ __align__(16) float e_part[16][512];   // per-d-group partials
    __shared__ __align__(16) float e_s[512];
    __shared__ __align__(16) float attn[512];
    __shared__ __align__(16) float ctx_part[16][256];
    __shared__ __align__(16) float ctx_s[256];
    __shared__ __align__(16) float gates_h[1024];     // h@WhhT partial (from merged phase 2)
    __shared__ __align__(16) float g_part[4][1024];
    __shared__ __align__(16) float gates[1024];

    if (tid < 256){
        h_s[tid] = 0.f; c_s[tid] = 0.f;
        __builtin_nontemporal_store(0.f, out + (size_t)b * 256 + tid);   // out[0] = zeros
    }
    __syncthreads();

    const float* projTb = g_projT + (size_t)b * 256 * 512;   // [d][s]
    const float* memb   = memory + (size_t)b * 256;

    for (int t = 1; t < T_STEPS; ++t){
        // E-row prefetch: issued now, consumed after phase 5 (hides LLC latency)
        float ev = __builtin_nontemporal_load(
                        g_E + ((size_t)t * B_SZ + b) * 1024 + tid);

        // ---- phase 1: hWh[d] = sum_k h[k] * W_h[d][k] ----
        {
            int d = tid & 255, kq = tid >> 8;   // kq in 0..3, 64 k's each
            float acc = 0.f;
            const float* wp = g_WhT + (size_t)(kq * 64) * 256 + d;
            #pragma unroll 8
            for (int k = 0; k < 64; ++k)
                acc += h_s[kq * 64 + k] * wp[(size_t)k * 256];
            hWh_part[kq][d] = acc;
        }
        __syncthreads();
        if (tid < 256)
            hWh[tid] = hWh_part[0][tid] + hWh_part[1][tid] + hWh_part[2][tid] + hWh_part[3][tid];
        __syncthreads();

        // ---- phase 2 (+ hidden h@WhhT): wave w owns d-slice [16w,16w+16)
        // for the energy sum AND j-column block [64w,64w+64) of h@WhhT.
        // The 16 scalar WhhT loads+FMAs per dd fill the latency slack of the
        // tanh chains; the full 1 MB WhhT stream hides under phase 2.
        {
            const float* pT  = projTb + (size_t)(wave * 16) * 512 + lane * 8;
            const float* whh = g_WhhT + wave * 64 + lane;   // col j = 64*wave+lane = tid
            float gh = 0.f;
            float4 aA = {0.f,0.f,0.f,0.f}, aB = {0.f,0.f,0.f,0.f};
            #pragma unroll 2
            for (int dd = 0; dd < 16; ++dd){
                float hw = hWh[wave * 16 + dd];
                const float4* rp = (const float4*)(pT + (size_t)dd * 512);
                float4 q1 = rp[0];
                float4 q2 = rp[1];
                #pragma unroll
                for (int kk = 0; kk < 16; ++kk){
                    int k = dd * 16 + kk;
                    gh += h_s[k] * whh[(size_t)k * 1024];
                }
                aA.x += tanh_f(q1.x + hw); aA.y += tanh_f(q1.y + hw);
                aA.z += tanh_f(q1.z + hw); aA.w += tanh_f(q1.w + hw);
                aB.x += tanh_f(q2.x + hw); aB.y += tanh_f(q2.y + hw);
                aB.z += tanh_f(q2.z + hw); aB.w += tanh_f(q2.w + hw);
            }
            float4* ep = (float4*)&e_part[wave][lane * 8];
            ep[0] = aA; ep[1] = aB;
            gates_h[tid] = gh;          // j == tid
        }
        __syncthreads();
        if (tid < 512){
            float v = 0.f;
            #pragma unroll
            for (int w2 = 0; w2 < 16; ++w2) v += e_part[w2][tid];
            e_s[tid] = v;
        }
        __syncthreads();

        // ---- phase 3: softmax over s (wave 0 only) ----
        if (wave == 0){
            float v[8]; float mx = -1e30f;
            #pragma unroll
            for (int i = 0; i < 8; ++i){ v[i] = e_s[lane + 64 * i]; mx = fmaxf(mx, v[i]); }
            #pragma unroll
            for (int m = 32; m; m >>= 1) mx = fmaxf(mx, __shfl_xor(mx, m, 64));
            float zs = 0.f;
            #pragma unroll
            for (int i = 0; i < 8; ++i){ v[i] = __expf(v[i] - mx); zs += v[i]; }
            #pragma unroll
            for (int m = 32; m; m >>= 1) zs += __shfl_xor(zs, m, 64);
            float inv = 1.f / zs;
            #pragma unroll
            for (int i = 0; i < 8; ++i) attn[lane + 64 * i] = v[i] * inv;
        }
        __syncthreads();

        // ---- phase 4: ctx[e] = sum_s attn[s]*mem[s][e] ----
        {
            int e4 = tid & 63, sq = tid >> 6;   // 16 s-groups x 32 s
            float a0=0.f, a1=0.f, a2=0.f, a3=0.f;
            const float* mp = memb + (size_t)(sq * 32) * 32768 + 4 * e4;
            #pragma unroll 4
            for (int s = 0; s < 32; ++s){
                float av = attn[sq * 32 + s];
                float4 w = *(const float4*)(mp + (size_t)s * 32768);
                a0 += av * w.x; a1 += av * w.y;
                a2 += av * w.z; a3 += av * w.w;
            }
            float4 r; r.x=a0; r.y=a1; r.z=a2; r.w=a3;
            ((float4*)ctx_part[sq])[e4] = r;
        }
        __syncthreads();
        if (tid < 256){
            float s = 0.f;
            #pragma unroll
            for (int g = 0; g < 16; ++g) s += ctx_part[g][tid];
            ctx_s[tid] = s;
        }
        __syncthreads();

        // ---- phase 5 (ctx half only): g_part[kh][j] = ctx_kh @ Wc.T ----
        {
            int jq = tid & 255, kh = tid >> 8;  // 4 j's per thread, 64 ctx-k's each
            float a0=0.f, a1=0.f, a2=0.f, a3=0.f;
            const float* src = ctx_s + kh * 64;
            const float* wp  = g_WihT + (size_t)(256 + kh * 64) * 1024 + 4 * jq;
            #pragma unroll 4
            for (int k = 0; k < 64; ++k){
                float xv = src[k];
                float4 w = *(const float4*)(wp + (size_t)k * 1024);
                a0 += xv * w.x; a1 += xv * w.y;
                a2 += xv * w.z; a3 += xv * w.w;
            }
            float4 r; r.x=a0; r.y=a1; r.z=a2; r.w=a3;
            ((float4*)g_part[kh])[jq] = r;
        }
        __syncthreads();
        gates[tid] = g_part[0][tid] + g_part[1][tid] + g_part[2][tid]
                   + g_part[3][tid] + gates_h[tid] + ev + g_bias[tid];
        __syncthreads();

        // ---- phase 6: LSTM cell, write h ----
        if (tid < 256){
            float ig = sigm_f(gates[tid]);
            float fg = sigm_f(gates[256 + tid]);
            float gg = tanh_f(gates[512 + tid]);
            float og = sigm_f(gates[768 + tid]);
            float cn = fg * c_s[tid] + ig * gg;
            float hn = og * tanh_f(cn);
            c_s[tid] = cn; h_s[tid] = hn;
            __builtin_nontemporal_store(hn, out + ((size_t)t * B_SZ + b) * 256 + tid);
        }
        __syncthreads();
    }
}

extern "C" void kernel_launch(void* const* d_in, const int* in_sizes, int n_in,
                              void* d_out, int out_size, void* d_ws, size_t ws_size,
                              hipStream_t stream){
    const float* tgt    = (const float*)d_in[0];
    const float* memory = (const float*)d_in[1];
    const float* W_attn = (const float*)d_in[2];
    const float* b_attn = (const float*)d_in[3];
    const float* W_ih   = (const float*)d_in[4];
    const float* W_hh   = (const float*)d_in[5];
    const float* b_ih   = (const float*)d_in[6];
    const float* b_hh   = (const float*)d_in[7];
    float* out = (float*)d_out;
    (void)d_ws; (void)ws_size; (void)in_sizes; (void)n_in; (void)out_size;

    pack_attn<<<256, 256, 0, stream>>>(W_attn);
    pack_wih<<<2048, 256, 0, stream>>>(W_ih);
    pack_whh<<<1024, 256, 0, stream>>>(W_hh);
    pack_bias<<<4, 256, 0, stream>>>(b_ih, b_hh);
    emb_gemm<<<dim3(512, 16), 256, 0, stream>>>(tgt);
    mem_projT_gemm<<<dim3(4, 1024), 256, 0, stream>>>(memory, W_attn, b_attn);
    decode_scan<<<128, 1024, 0, stream>>>(memory, out);
}

// Round 9
// 13224.432 us; speedup vs baseline: 1.3677x; 1.3677x over previous
//
#include <hip/hip_runtime.h>
#include <string.h>

#define T_STEPS 256
#define B_SZ    128
#define S_SZ    512
#define D_SZ    256
#define NG      1024   // 4*HID

// ---- static device scratch (graph-capture safe, ws_size-independent) ----
__device__ float g_projT[(size_t)B_SZ * 256 * 512];     // 64 MiB, [b][d][s] fp32 (TRANSPOSED)
__device__ float g_E[(size_t)T_STEPS * B_SZ * 1024];    // 128 MiB, [t][b][j]: emb@W_ih_emb.T
__device__ float g_WihT[512 * 1024];                    // [k][j] fp32 (k<256 emb rows, k>=256 ctx rows)
__device__ float g_WhhT[256 * 1024];                    // [k][j] fp32
__device__ float g_WhT [256 * 256];                     // [k][d] fp32
__device__ float g_bias[1024];

__device__ __forceinline__ float tanh_f(float x){
    float r = __expf(2.f * x);          // exp(+inf)=inf, exp(-inf)=0 -> no NaN
    return 1.f - 2.f / (r + 1.f);
}
__device__ __forceinline__ float sigm_f(float x){
    return 1.f / (1.f + __expf(-x));
}

// ---- packing kernels ----
__global__ void pack_attn(const float* __restrict__ W_attn){
    int id = blockIdx.x * 256 + threadIdx.x;   // 65536
    int d = id >> 8, k = id & 255;
    g_WhT[k * 256 + d] = W_attn[d * 512 + k];
}
__global__ void pack_wih(const float* __restrict__ W){
    int id = blockIdx.x * 256 + threadIdx.x;   // 524288
    int j = id >> 9, k = id & 511;
    g_WihT[k * 1024 + j] = W[id];
}
__global__ void pack_whh(const float* __restrict__ W){
    int id = blockIdx.x * 256 + threadIdx.x;   // 262144
    int j = id >> 8, k = id & 255;
    g_WhhT[k * 1024 + j] = W[id];
}
__global__ void pack_bias(const float* __restrict__ bih, const float* __restrict__ bhh){
    int j = blockIdx.x * 256 + threadIdx.x;    // 1024
    g_bias[j] = bih[j] + bhh[j];
}

// g_projT[b][d][s] = sum_e memory[s][b][e] * W_attn[d][256+e] + b_attn[d]
__global__ __launch_bounds__(256) void mem_projT_gemm(
        const float* __restrict__ memory,     // [S][B][256] fp32
        const float* __restrict__ W_attn,     // [256][512] fp32
        const float* __restrict__ b_attn){
    __shared__ float As[32][65];   // [e'][d']
    __shared__ float Bs[32][65];   // [e'][r']
    int tid = threadIdx.x;
    int tm = tid >> 4, tn = tid & 15;
    int row0 = blockIdx.x * 64;              // d tile
    int col0 = blockIdx.y * 64;              // r tile (64 | 512 so one b per tile)
    float acc[4][4] = {};
    for (int k0 = 0; k0 < 256; k0 += 32){
        int m = tid >> 2, kq = tid & 3;
        const float* ap = W_attn + (size_t)(row0 + m) * 512 + 256 + k0 + kq * 8;
        #pragma unroll
        for (int i = 0; i < 8; ++i) As[kq * 8 + i][m] = ap[i];
        int r  = col0 + m;
        int bb = r >> 9, ss = r & 511;
        const float* bp = memory + ((size_t)ss * B_SZ + bb) * 256 + k0 + kq * 8;
        #pragma unroll
        for (int i = 0; i < 8; ++i) Bs[kq * 8 + i][m] = bp[i];
        __syncthreads();
        #pragma unroll
        for (int k2 = 0; k2 < 32; ++k2){
            float a[4], bv[4];
            #pragma unroll
            for (int i = 0; i < 4; ++i) a[i]  = As[k2][tm * 4 + i];
            #pragma unroll
            for (int i = 0; i < 4; ++i) bv[i] = Bs[k2][tn * 4 + i];
            #pragma unroll
            for (int i = 0; i < 4; ++i)
                #pragma unroll
                for (int j = 0; j < 4; ++j) acc[i][j] += a[i] * bv[j];
        }
        __syncthreads();
    }
    int bb_o = col0 >> 9;
    int s_o  = (col0 & 511) + tn * 4;
    #pragma unroll
    for (int i = 0; i < 4; ++i){
        int d = row0 + tm * 4 + i;
        float bi = b_attn[d];
        float* pp = g_projT + ((size_t)bb_o * 256 + d) * 512 + s_o;
        #pragma unroll
        for (int j = 0; j < 4; ++j)
            pp[j] = acc[i][j] + bi;       // coalesced along s
    }
}

// g_E [r=t*B+b][j] = tgt[r][:256] @ g_WihT[k<256][j]
__global__ __launch_bounds__(256) void emb_gemm(
        const float* __restrict__ tgt){       // [T][B][256] fp32
    __shared__ float As[32][65];
    __shared__ float Bs[32][65];
    int tid = threadIdx.x;
    int tm = tid >> 4, tn = tid & 15;
    int row0 = blockIdx.x * 64;
    int col0 = blockIdx.y * 64;
    float acc[4][4] = {};
    for (int k0 = 0; k0 < 256; k0 += 32){
        int m = tid >> 2, kq = tid & 3;
        const float* ap = tgt + (size_t)(row0 + m) * 256 + k0 + kq * 8;
        #pragma unroll
        for (int i = 0; i < 8; ++i) As[kq * 8 + i][m] = ap[i];
        int kk = tid >> 3, dq = tid & 7;
        const float* bp = g_WihT + (size_t)(k0 + kk) * 1024 + col0 + dq * 8;
        #pragma unroll
        for (int i = 0; i < 8; ++i) Bs[kk][dq * 8 + i] = bp[i];
        __syncthreads();
        #pragma unroll
        for (int k2 = 0; k2 < 32; ++k2){
            float a[4], bv[4];
            #pragma unroll
            for (int i = 0; i < 4; ++i) a[i]  = As[k2][tm * 4 + i];
            #pragma unroll
            for (int i = 0; i < 4; ++i) bv[i] = Bs[k2][tn * 4 + i];
            #pragma unroll
            for (int i = 0; i < 4; ++i)
                #pragma unroll
                for (int j = 0; j < 4; ++j) acc[i][j] += a[i] * bv[j];
        }
        __syncthreads();
    }
    #pragma unroll
    for (int i = 0; i < 4; ++i){
        int r = row0 + tm * 4 + i;
        float* pp = g_E + (size_t)r * 1024 + col0 + tn * 4;
        #pragma unroll
        for (int j = 0; j < 4; ++j)
            __builtin_nontemporal_store(acc[i][j], pp + j);
    }
}

// ---- main persistent scan: one block per batch element, 1024 threads ----
__global__ __launch_bounds__(1024) void decode_scan(
        const float* __restrict__ memory,    // [S][B][256] fp32
        float* __restrict__ out)             // [T][B][256] fp32
{
    const int b    = blockIdx.x;
    const int tid  = threadIdx.x;
    const int lane = tid & 63;
    const int wave = tid >> 6;          // 16 waves

    __shared__ __align__(16) float h_s[256];
    __shared__ __align__(16) float c_s[256];
    __shared__ __align__(16) float hWh_part[4][256];
    __shared__ __align__(16) float e_part[16][512];   // per-d-group partials
    __shared__ __align__(16) float e_s[512];
    __shared__ __align__(16) float attn[512];
    __shared__ __align__(16) float ctx_part[16][256];
    __shared__ __align__(16) float ctx_s[256];
    __shared__ __align__(16) float g_part[8][1024];   // 8 k-groups
    __shared__ __align__(16) float gates[1024];

    if (tid < 256){
        h_s[tid] = 0.f; c_s[tid] = 0.f;
        __builtin_nontemporal_store(0.f, out + (size_t)b * 256 + tid);   // out[0] = zeros
    }
    __syncthreads();

    const float* projTb = g_projT + (size_t)b * 256 * 512;   // [d][s]
    const float* memb   = memory + (size_t)b * 256;

    for (int t = 1; t < T_STEPS; ++t){
        // E-row prefetch: issued now, consumed after phase 5 (hides LLC latency)
        float ev = __builtin_nontemporal_load(
                        g_E + ((size_t)t * B_SZ + b) * 1024 + tid);

        // ---- phase 1: hWh_part[kq][d] = partial sums of h[k]*W_h[d][k] ----
        {
            int d = tid & 255, kq = tid >> 8;   // kq in 0..3, 64 k's each
            float acc = 0.f;
            const float* wp = g_WhT + (size_t)(kq * 64) * 256 + d;
            #pragma unroll 8
            for (int k = 0; k < 64; ++k)
                acc += h_s[kq * 64 + k] * wp[(size_t)k * 256];
            hWh_part[kq][d] = acc;
        }
        __syncthreads();

        // ---- phase 2: wave w owns d-slice [16w,16w+16), lane owns 8 s.
        // hWh summed in-register from the 4 partials (uniform LDS broadcast),
        // no separate reduce pass/barrier. Coalesced 2KB wave reads; no shuffles.
        {
            const float* pT = projTb + (size_t)(wave * 16) * 512 + lane * 8;
            float4 aA = {0.f,0.f,0.f,0.f}, aB = {0.f,0.f,0.f,0.f};
            #pragma unroll 2
            for (int dd = 0; dd < 16; ++dd){
                int d = wave * 16 + dd;
                float hw = hWh_part[0][d] + hWh_part[1][d]
                         + hWh_part[2][d] + hWh_part[3][d];
                const float4* rp = (const float4*)(pT + (size_t)dd * 512);
                float4 q1 = rp[0];
                float4 q2 = rp[1];
                aA.x += tanh_f(q1.x + hw); aA.y += tanh_f(q1.y + hw);
                aA.z += tanh_f(q1.z + hw); aA.w += tanh_f(q1.w + hw);
                aB.x += tanh_f(q2.x + hw); aB.y += tanh_f(q2.y + hw);
                aB.z += tanh_f(q2.z + hw); aB.w += tanh_f(q2.w + hw);
            }
            float4* ep = (float4*)&e_part[wave][lane * 8];
            ep[0] = aA; ep[1] = aB;
        }
        __syncthreads();
        if (tid < 512){
            float v = 0.f;
            #pragma unroll
            for (int w2 = 0; w2 < 16; ++w2) v += e_part[w2][tid];
            e_s[tid] = v;
        }
        __syncthreads();

        // ---- phase 3: softmax over s (wave 0 only) ----
        if (wave == 0){
            float v[8]; float mx = -1e30f;
            #pragma unroll
            for (int i = 0; i < 8; ++i){ v[i] = e_s[lane + 64 * i]; mx = fmaxf(mx, v[i]); }
            #pragma unroll
            for (int m = 32; m; m >>= 1) mx = fmaxf(mx, __shfl_xor(mx, m, 64));
            float zs = 0.f;
            #pragma unroll
            for (int i = 0; i < 8; ++i){ v[i] = __expf(v[i] - mx); zs += v[i]; }
            #pragma unroll
            for (int m = 32; m; m >>= 1) zs += __shfl_xor(zs, m, 64);
            float inv = 1.f / zs;
            #pragma unroll
            for (int i = 0; i < 8; ++i) attn[lane + 64 * i] = v[i] * inv;
        }
        __syncthreads();

        // ---- phase 4: ctx[e] = sum_s attn[s]*mem[s][e] (unroll 8) ----
        {
            int e4 = tid & 63, sq = tid >> 6;   // 16 s-groups x 32 s
            float a0=0.f, a1=0.f, a2=0.f, a3=0.f;
            const float* mp = memb + (size_t)(sq * 32) * 32768 + 4 * e4;
            #pragma unroll 8
            for (int s = 0; s < 32; ++s){
                float av = attn[sq * 32 + s];
                float4 w = *(const float4*)(mp + (size_t)s * 32768);
                a0 += av * w.x; a1 += av * w.y;
                a2 += av * w.z; a3 += av * w.w;
            }
            float4 r; r.x=a0; r.y=a1; r.z=a2; r.w=a3;
            ((float4*)ctx_part[sq])[e4] = r;
        }
        __syncthreads();
        if (tid < 256){
            float s = 0.f;
            #pragma unroll
            for (int g = 0; g < 16; ++g) s += ctx_part[g][tid];
            ctx_s[tid] = s;
        }
        __syncthreads();

        // ---- phase 5: gates = ctx@Wc.T + h@W_hh.T, 8 k-groups x 64 k,
        //      8 j's per thread (two float4 accumulators) ----
        {
            int jq = tid & 127, kh = tid >> 7;  // kh 0..7
            int j0 = jq * 8;
            float4 acc0 = {0.f,0.f,0.f,0.f}, acc1 = {0.f,0.f,0.f,0.f};
            const float* src;
            const float* wp;
            if (kh < 4){
                src = ctx_s + kh * 64;
                wp  = g_WihT + (size_t)(256 + kh * 64) * 1024 + j0;
            } else {
                src = h_s + (kh - 4) * 64;
                wp  = g_WhhT + (size_t)((kh - 4) * 64) * 1024 + j0;
            }
            #pragma unroll 4
            for (int k = 0; k < 64; ++k){
                float xv = src[k];
                const float4* wr = (const float4*)(wp + (size_t)k * 1024);
                float4 w0 = wr[0];
                float4 w1 = wr[1];
                acc0.x += xv * w0.x; acc0.y += xv * w0.y;
                acc0.z += xv * w0.z; acc0.w += xv * w0.w;
                acc1.x += xv * w1.x; acc1.y += xv * w1.y;
                acc1.z += xv * w1.z; acc1.w += xv * w1.w;
            }
            float4* gp = (float4*)&g_part[kh][j0];
            gp[0] = acc0; gp[1] = acc1;
        }
        __syncthreads();
        gates[tid] = ((g_part[0][tid] + g_part[1][tid]) + (g_part[2][tid] + g_part[3][tid]))
                   + ((g_part[4][tid] + g_part[5][tid]) + (g_part[6][tid] + g_part[7][tid]))
                   + ev + g_bias[tid];
        __syncthreads();

        // ---- phase 6: LSTM cell, write h ----
        if (tid < 256){
            float ig = sigm_f(gates[tid]);
            float fg = sigm_f(gates[256 + tid]);
            float gg = tanh_f(gates[512 + tid]);
            float og = sigm_f(gates[768 + tid]);
            float cn = fg * c_s[tid] + ig * gg;
            float hn = og * tanh_f(cn);
            c_s[tid] = cn; h_s[tid] = hn;
            __builtin_nontemporal_store(hn, out + ((size_t)t * B_SZ + b) * 256 + tid);
        }
        __syncthreads();
    }
}

extern "C" void kernel_launch(void* const* d_in, const int* in_sizes, int n_in,
                              void* d_out, int out_size, void* d_ws, size_t ws_size,
                              hipStream_t stream){
    const float* tgt    = (const float*)d_in[0];
    const float* memory = (const float*)d_in[1];
    const float* W_attn = (const float*)d_in[2];
    const float* b_attn = (const float*)d_in[3];
    const float* W_ih   = (const float*)d_in[4];
    const float* W_hh   = (const float*)d_in[5];
    const float* b_ih   = (const float*)d_in[6];
    const float* b_hh   = (const float*)d_in[7];
    float* out = (float*)d_out;
    (void)d_ws; (void)ws_size; (void)in_sizes; (void)n_in; (void)out_size;

    pack_attn<<<256, 256, 0, stream>>>(W_attn);
    pack_wih<<<2048, 256, 0, stream>>>(W_ih);
    pack_whh<<<1024, 256, 0, stream>>>(W_hh);
    pack_bias<<<4, 256, 0, stream>>>(b_ih, b_hh);
    emb_gemm<<<dim3(512, 16), 256, 0, stream>>>(tgt);
    mem_projT_gemm<<<dim3(4, 1024), 256, 0, stream>>>(memory, W_attn, b_attn);
    decode_scan<<<128, 1024, 0, stream>>>(memory, out);
}